// Round 5
// baseline (33.581 us; speedup 1.0000x reference)
//
#include <hip/hip_runtime.h>

#define NBATCH 4096
#define NT 2048
#define NP 1024
#define NTH 256
#define EPT 8   // NT elements per thread
#define MSZ 1022          // interior system size (NP-2)
#define KT 6              // conv half-width: |rho|^7 ~ 1e-4 -> ~1e-10 in spline value
#define PAD 8             // left zero-pad of rhs (16B-aligned windows)
#define IMGW 14           // boundary image reach
#define RPSZ 1040         // PAD + MSZ + 10 tail zeros

__global__ __launch_bounds__(NTH, 8) void w2loss_kernel(
    const float* __restrict__ f,
    const float* __restrict__ obs,
    float* __restrict__ partial)
{
    __shared__ float2 sQM[NP];                    // .x = q_k, .y = M_k
    __shared__ __align__(16) float sRp[RPSZ];     // zero-padded rhs
    __shared__ float  sCB[NTH];                   // per-thread boundary cdf
    __shared__ float  sPow[IMGW];                 // rho^d
    __shared__ float  sWSA[4], sWSB[4];
    __shared__ float  sSqA[2], sSqB[2];
    __shared__ float  sRed[4];

    const int tid  = threadIdx.x;
    const int lane = tid & 63;
    const int wid  = tid >> 6;
    const int b    = blockIdx.x;
    const int base = tid * EPT;

    const float dt      = 0.001f;
    const float half_dt = 0.0005f;
    const float h       = 0.00097751710654936461f;  // 1/1023
    const float inv_h   = 1023.0f;
    const float inv_h2  = 1046529.0f;               // 1023^2

    const float* orow = obs + (size_t)b * NT;
    const float* frow = f   + (size_t)b * NT;
    float4 o0 = *reinterpret_cast<const float4*>(orow + base);
    float4 o1 = *reinterpret_cast<const float4*>(orow + base + 4);
    float4 g0 = *reinterpret_cast<const float4*>(frow + base);
    float4 g1 = *reinterpret_cast<const float4*>(frow + base + 4);

    if (tid < IMGW) {
        const float rho = -0.26794919243112270f;
        float v = 1.0f;
        for (int i = 0; i < tid; ++i) v *= rho;
        sPow[tid] = v;
    }
    if (tid < PAD) { sRp[tid] = 0.0f; sRp[1032 + tid] = 0.0f; }

    // ---- squares + per-thread prefixes for BOTH rows ----
    float prefA[EPT], prefB[EPT];
    {
        float s0;
        s0 = o0.x*o0.x; prefA[0] = s0;
        s0 = o0.y*o0.y; prefA[1] = prefA[0] + s0;
        s0 = o0.z*o0.z; prefA[2] = prefA[1] + s0;
        s0 = o0.w*o0.w; prefA[3] = prefA[2] + s0;
        s0 = o1.x*o1.x; prefA[4] = prefA[3] + s0;
        s0 = o1.y*o1.y; prefA[5] = prefA[4] + s0;
        s0 = o1.z*o1.z; prefA[6] = prefA[5] + s0;
        s0 = o1.w*o1.w; prefA[7] = prefA[6] + s0;
        s0 = g0.x*g0.x; prefB[0] = s0;
        s0 = g0.y*g0.y; prefB[1] = prefB[0] + s0;
        s0 = g0.z*g0.z; prefB[2] = prefB[1] + s0;
        s0 = g0.w*g0.w; prefB[3] = prefB[2] + s0;
        s0 = g1.x*g1.x; prefB[4] = prefB[3] + s0;
        s0 = g1.y*g1.y; prefB[5] = prefB[4] + s0;
        s0 = g1.z*g1.z; prefB[6] = prefB[5] + s0;
        s0 = g1.w*g1.w; prefB[7] = prefB[6] + s0;
    }
    float sqA7 = o1.w * o1.w;
    float sqB7 = g1.w * g1.w;

    // ---- interleaved wave scans (2x ILP) ----
    float tsA = prefA[EPT - 1], tsB = prefB[EPT - 1];
    float wsA = tsA, wsB = tsB;
#pragma unroll
    for (int off = 1; off < 64; off <<= 1) {
        float uA = __shfl_up(wsA, off);
        float uB = __shfl_up(wsB, off);
        if (lane >= off) { wsA += uA; wsB += uB; }
    }
    if (lane == 63) { sWSA[wid] = wsA; sWSB[wid] = wsB; }
    if (tid == 0)       { sSqA[0] = prefA[0]; sSqB[0] = prefB[0]; }
    if (tid == NTH - 1) { sSqA[1] = sqA7;     sSqB[1] = sqB7; }
    __syncthreads();                                            // B1

    float exclA = wsA - tsA, exclB = wsB - tsB;
    if (wid > 0) { exclA += sWSA[0]; exclB += sWSB[0]; }
    if (wid > 1) { exclA += sWSA[1]; exclB += sWSB[1]; }
    if (wid > 2) { exclA += sWSA[2]; exclB += sWSB[2]; }
    float totA = sWSA[0] + sWSA[1] + sWSA[2] + sWSA[3];
    float totB = sWSB[0] + sWSB[1] + sWSB[2] + sWSB[3];
    float sq0A = sSqA[0], sq0B = sSqB[0];
    float invSA = 1.0f / (half_dt * (2.0f * totA - sSqA[1] - sq0A));
    float invSB = 1.0f / (half_dt * (2.0f * totB - sSqB[1] - sq0B));

    // boundary cdf handoff: c at j = base+7
    {
        float c7 = half_dt * ((exclA + prefA[6]) + (exclA + prefA[7]) - sq0A) * invSA;
        sCB[tid] = c7;
    }
    __syncthreads();                                            // B2

    // ---- inverse-CDF by forward scatter: j claims p_k in (c_{j-1}, c_j] ----
    {
        float cm = (tid == 0) ? -1.0f : sCB[tid - 1];
        float Pm = exclA;
#pragma unroll
        for (int e = 0; e < EPT; ++e) {
            int j = base + e;
            float Pj = exclA + prefA[e];
            float cc = (j == 0) ? 0.0f : half_dt * (Pm + Pj - sq0A) * invSA;
            int kLo = (int)floorf(cm * inv_h) + 1;
            int kHi = (int)floorf(cc * inv_h);
            if (kLo < 0) kLo = 0;
            if (j == NT - 1) kHi = NP - 1;          // guarantee k=1023 coverage
            else if (kHi > NP - 1) kHi = NP - 1;
            float qv = (float)j * dt;
            for (int k = kLo; k <= kHi; ++k) sQM[k].x = qv;
            cm = cc;
            Pm = Pj;
        }
    }
    __syncthreads();                                            // B3

    // ---- rhs (consecutive-i, aligned vector store) ----
    {
        int i0 = tid * 4;
        float q0 = sQM[i0].x;
        float q1 = sQM[i0 + 1].x;
        float q2 = sQM[i0 + 2].x;
        float q3 = sQM[i0 + 3].x;
        int i4 = i0 + 4 > 1023 ? 1023 : i0 + 4;
        int i5 = i0 + 5 > 1023 ? 1023 : i0 + 5;
        float q4 = sQM[i4].x;
        float q5 = sQM[i5].x;
        float4 r;
        r.x = 6.0f * (q0 - 2.0f * q1 + q2) * inv_h2;
        r.y = 6.0f * (q1 - 2.0f * q2 + q3) * inv_h2;
        r.z = (i0 + 2 < MSZ) ? 6.0f * (q2 - 2.0f * q3 + q4) * inv_h2 : 0.0f;
        r.w = (i0 + 3 < MSZ) ? 6.0f * (q3 - 2.0f * q4 + q5) * inv_h2 : 0.0f;
        *reinterpret_cast<float4*>(sRp + PAD + i0) = r;
    }
    __syncthreads();                                            // B4

    // ---- tridiagonal solve: windowed conv (b128 loads) + boundary images ----
    {
        const float Cg = 0.28867513459481288f; // 1/(2*sqrt(3))
        const float CP[KT + 1] = {
            1.0f, -0.26794919243112270f, 0.071796769724490830f,
            -0.019237886466840586f, 0.0051547761428899979f,
            -0.0013812184239975285f, 0.00037009627398250260f };
        int i0 = tid * 4;
        const float4* wp = reinterpret_cast<const float4*>(sRp + i0); // 16B-aligned
        float4 a0 = wp[0], a1 = wp[1], a2 = wp[2], a3 = wp[3], a4 = wp[4];
        float w[20] = { a0.x, a0.y, a0.z, a0.w,
                        a1.x, a1.y, a1.z, a1.w,
                        a2.x, a2.y, a2.z, a2.w,
                        a3.x, a3.y, a3.z, a3.w,
                        a4.x, a4.y, a4.z, a4.w };
        float m[4];
#pragma unroll
        for (int e = 0; e < 4; ++e) {
            float acc = CP[0] * w[PAD + e];
#pragma unroll
            for (int d = 1; d <= KT; ++d)
                acc += CP[d] * (w[PAD + e - d] + w[PAD + e + d]);
            m[e] = acc;
        }
        if (i0 <= 12) {                       // some e has i+1 < IMGW
            float T1 = 0.0f;
#pragma unroll
            for (int k2 = 0; k2 < IMGW - 1; ++k2) T1 += sPow[k2 + 1] * sRp[PAD + k2];
#pragma unroll
            for (int e = 0; e < 4; ++e) {
                int i = i0 + e;
                if (i + 1 < IMGW) m[e] -= sPow[i + 1] * T1;
            }
        }
        if (i0 + 3 > MSZ - IMGW) {            // some e has MSZ - i < IMGW
            float T2 = 0.0f;
#pragma unroll
            for (int k2 = MSZ - IMGW + 1; k2 < MSZ; ++k2) T2 += sPow[MSZ - k2] * sRp[PAD + k2];
#pragma unroll
            for (int e = 0; e < 4; ++e) {
                int i = i0 + e;
                if (i < MSZ && MSZ - i < IMGW) m[e] -= sPow[MSZ - i] * T2;
            }
        }
#pragma unroll
        for (int e = 0; e < 4; ++e) {
            int i = i0 + e;
            if (i < MSZ) sQM[i + 1].y = Cg * m[e];
        }
    }
    if (tid == 0) { sQM[0].y = 0.0f; sQM[NP - 1].y = 0.0f; }
    __syncthreads();                                            // B5

    // ---- Phase B: F in registers, spline eval, integrate ----
    float local = 0.0f;
    float term0 = 0.0f, term7 = 0.0f;
    {
        float Pm = exclB;
#pragma unroll
        for (int e = 0; e < EPT; ++e) {
            int j = base + e;
            float Pj = exclB + prefB[e];
            float Fj = (j == 0) ? 0.0f : half_dt * (Pm + Pj - sq0B) * invSB;
            float sqe = (e == 0) ? prefB[0] : (prefB[e] - prefB[e - 1]);
            float ft = sqe * invSB;
            int k = (int)(Fj * inv_h);
            if (k < 0) k = 0;
            if (k > NP - 2) k = NP - 2;
            float s = Fj - (float)k * h;
            float2 qm0 = sQM[k];
            float2 qm1 = sQM[k + 1];
            float bco = (qm1.x - qm0.x) * inv_h - h * (2.0f * qm0.y + qm1.y) * (1.0f / 6.0f);
            float cco = 0.5f * qm0.y;
            float dco = (qm1.y - qm0.y) * (inv_h * (1.0f / 6.0f));
            float od  = qm0.x + s * (bco + s * (cco + s * dco));
            float tj  = (float)j * dt;
            float dd  = tj - od;
            float term = dd * dd * ft;
            local += term;
            if (e == 0) term0 = term;
            if (e == EPT - 1) term7 = term;
            Pm = Pj;
        }
    }
    if (tid == 0)       local -= 0.5f * term0;   // trapezoid half-weight at j=0
    if (tid == NTH - 1) local -= 0.5f * term7;   // and at j=NT-1

#pragma unroll
    for (int off = 32; off > 0; off >>= 1) local += __shfl_down(local, off);
    if (lane == 0) sRed[wid] = local;
    __syncthreads();                                            // B6
    if (tid == 0) partial[b] = (sRed[0] + sRed[1] + sRed[2] + sRed[3]) * dt;
}

// fixed-order deterministic reduction of 4096 partials -> scalar
__global__ __launch_bounds__(NTH) void w2loss_reduce(
    const float* __restrict__ partial, float* __restrict__ out)
{
    __shared__ float sRed[4];
    const int tid  = threadIdx.x;
    const int lane = tid & 63;
    const int wid  = tid >> 6;
    float s = 0.0f;
#pragma unroll
    for (int i = 0; i < 16; i += 4) {
        float4 v = *reinterpret_cast<const float4*>(partial + tid * 16 + i);
        s += v.x + v.y + v.z + v.w;
    }
#pragma unroll
    for (int off = 32; off > 0; off >>= 1) s += __shfl_down(s, off);
    if (lane == 0) sRed[wid] = s;
    __syncthreads();
    if (tid == 0) out[0] = sRed[0] + sRed[1] + sRed[2] + sRed[3];
}

extern "C" void kernel_launch(void* const* d_in, const int* in_sizes, int n_in,
                              void* d_out, int out_size, void* d_ws, size_t ws_size,
                              hipStream_t stream) {
    const float* f   = (const float*)d_in[0];
    const float* obs = (const float*)d_in[1];
    float* out     = (float*)d_out;
    float* partial = (float*)d_ws;   // 4096 floats = 16 KB scratch

    w2loss_kernel<<<NBATCH, NTH, 0, stream>>>(f, obs, partial);
    w2loss_reduce<<<1, NTH, 0, stream>>>(partial, out);
}

// Round 6
// 28.053 us; speedup vs baseline: 1.1971x; 1.1971x over previous
//
#include <hip/hip_runtime.h>

#define NBATCH 4096
#define NT 2048
#define NP 1024
#define NTH 256
#define EPT 8   // NT elements per thread
#define PPT 4   // NP items per thread
#define MSZ 1022          // interior system size (NP-2)
#define KT 6              // conv half-width: |rho|^7 ~ 1e-4 -> ~1e-10 in spline value
#define IMGW 14           // boundary image reach

__global__ __launch_bounds__(NTH, 4) void w2loss_kernel(
    const float* __restrict__ f,
    const float* __restrict__ obs,
    float* __restrict__ partial)
{
    __shared__ float2 sQM[NP];           // .x = q_k, .y = M_k
    __shared__ float  sRp[MSZ + 2 * KT]; // zero-padded rhs
    __shared__ float  sH[NTH];           // prev-thread last square handoff
    __shared__ float  sPow[IMGW];        // rho^d
    __shared__ float  sWSA[4], sWSB[4];
    __shared__ float  sSqA[2], sSqB[2];
    __shared__ float  sRed[4];

    const int tid  = threadIdx.x;
    const int lane = tid & 63;
    const int wid  = tid >> 6;
    const int b    = blockIdx.x;
    const int base = tid * EPT;

    const float dt      = 0.001f;
    const float half_dt = 0.0005f;
    const float h       = 0.00097751710654936461f;  // 1/1023
    const float inv_h   = 1023.0f;
    const float inv_h2  = 1046529.0f;               // 1023^2

    const float* orow = obs + (size_t)b * NT;
    const float* frow = f   + (size_t)b * NT;
    float4 o0 = *reinterpret_cast<const float4*>(orow + base);
    float4 o1 = *reinterpret_cast<const float4*>(orow + base + 4);
    float4 g0 = *reinterpret_cast<const float4*>(frow + base);
    float4 g1 = *reinterpret_cast<const float4*>(frow + base + 4);

    if (tid < IMGW) {
        const float rho = -0.26794919243112270f;
        float v = 1.0f;
        for (int i = 0; i < tid; ++i) v *= rho;
        sPow[tid] = v;
    }
    if (tid < KT) { sRp[tid] = 0.0f; sRp[KT + MSZ + tid] = 0.0f; }

    // ---- squares + per-thread prefixes for BOTH rows ----
    float prefA[EPT], prefB[EPT];
    {
        float s0;
        s0 = o0.x*o0.x; prefA[0] = s0;
        s0 = o0.y*o0.y; prefA[1] = prefA[0] + s0;
        s0 = o0.z*o0.z; prefA[2] = prefA[1] + s0;
        s0 = o0.w*o0.w; prefA[3] = prefA[2] + s0;
        s0 = o1.x*o1.x; prefA[4] = prefA[3] + s0;
        s0 = o1.y*o1.y; prefA[5] = prefA[4] + s0;
        s0 = o1.z*o1.z; prefA[6] = prefA[5] + s0;
        s0 = o1.w*o1.w; prefA[7] = prefA[6] + s0;
        s0 = g0.x*g0.x; prefB[0] = s0;
        s0 = g0.y*g0.y; prefB[1] = prefB[0] + s0;
        s0 = g0.z*g0.z; prefB[2] = prefB[1] + s0;
        s0 = g0.w*g0.w; prefB[3] = prefB[2] + s0;
        s0 = g1.x*g1.x; prefB[4] = prefB[3] + s0;
        s0 = g1.y*g1.y; prefB[5] = prefB[4] + s0;
        s0 = g1.z*g1.z; prefB[6] = prefB[5] + s0;
        s0 = g1.w*g1.w; prefB[7] = prefB[6] + s0;
    }
    float sqA7 = o1.w * o1.w;
    float sqB7 = g1.w * g1.w;
    sH[tid] = sqA7;                      // handoff BEFORE B1 (read after B1)

    // ---- interleaved wave scans (2x ILP) ----
    float tsA = prefA[EPT - 1], tsB = prefB[EPT - 1];
    float wsA = tsA, wsB = tsB;
#pragma unroll
    for (int off = 1; off < 64; off <<= 1) {
        float uA = __shfl_up(wsA, off);
        float uB = __shfl_up(wsB, off);
        if (lane >= off) { wsA += uA; wsB += uB; }
    }
    if (lane == 63) { sWSA[wid] = wsA; sWSB[wid] = wsB; }
    if (tid == 0)       { sSqA[0] = prefA[0]; sSqB[0] = prefB[0]; }
    if (tid == NTH - 1) { sSqA[1] = sqA7;     sSqB[1] = sqB7; }
    __syncthreads();                                            // B1

    float exclA = wsA - tsA, exclB = wsB - tsB;
    if (wid > 0) { exclA += sWSA[0]; exclB += sWSB[0]; }
    if (wid > 1) { exclA += sWSA[1]; exclB += sWSB[1]; }
    if (wid > 2) { exclA += sWSA[2]; exclB += sWSB[2]; }
    float totA = sWSA[0] + sWSA[1] + sWSA[2] + sWSA[3];
    float totB = sWSB[0] + sWSB[1] + sWSB[2] + sWSB[3];
    float sq0A = sSqA[0], sq0B = sSqB[0];
    float invSA = 1.0f / (half_dt * (2.0f * totA - sSqA[1] - sq0A));
    float invSB = 1.0f / (half_dt * (2.0f * totB - sSqB[1] - sq0B));

    // ---- inverse-CDF by forward scatter: j claims p_k in (c_{j-1}, c_j] ----
    // boundary cm reconstructed from handed-off prev-thread last square; any
    // ulp-level partition mismatch is covered by the +1 claim extension at e=7.
    {
        float cm;
        if (tid == 0) cm = -1.0f;
        else {
            float sqprev = sH[tid - 1];
            cm = half_dt * (((exclA - sqprev) + exclA) - sq0A) * invSA;
        }
        float Pm = exclA;
#pragma unroll
        for (int e = 0; e < EPT; ++e) {
            int j = base + e;
            float Pj = exclA + prefA[e];
            float cc = (j == 0) ? 0.0f : half_dt * (Pm + Pj - sq0A) * invSA;
            int kLo = (int)floorf(cm * inv_h) + 1;
            int kHi = (int)floorf(cc * inv_h);
            if (kLo < 0) kLo = 0;
            if (j == NT - 1) kHi = NP - 1;          // guarantee k=1023 coverage
            else {
                if (e == EPT - 1) kHi += 1;         // bridge thread-boundary ulp gap
                if (kHi > NP - 1) kHi = NP - 1;
            }
            float qv = (float)j * dt;
            for (int k = kLo; k <= kHi; ++k) sQM[k].x = qv;
            cm = cc;
            Pm = Pj;
        }
    }
    __syncthreads();                                            // B2

    // ---- rhs (strided, conflict-free) ----
#pragma unroll
    for (int kk = 0; kk < PPT; ++kk) {
        int i = tid + kk * NTH;
        if (i < MSZ)
            sRp[KT + i] = 6.0f * (sQM[i].x - 2.0f * sQM[i + 1].x + sQM[i + 2].x) * inv_h2;
    }
    __syncthreads();                                            // B3

    // ---- tridiagonal solve: constant-tap conv + redundant boundary images ----
    {
        const float Cg = 0.28867513459481288f; // 1/(2*sqrt(3))
        const float CP[KT + 1] = {
            1.0f, -0.26794919243112270f, 0.071796769724490830f,
            -0.019237886466840586f, 0.0051547761428899979f,
            -0.0013812184239975285f, 0.00037009627398250260f };
#pragma unroll
        for (int kk = 0; kk < PPT; ++kk) {
            int i = tid + kk * NTH;
            if (i < MSZ) {
                float acc = 0.0f;
#pragma unroll
                for (int d = -KT; d <= KT; ++d) {
                    int ad = d < 0 ? -d : d;
                    acc += CP[ad] * sRp[KT + i + d];
                }
                if (i + 1 < IMGW) {
                    float t1 = 0.0f;
#pragma unroll
                    for (int k2 = 0; k2 < IMGW - 1; ++k2) t1 += sPow[k2 + 1] * sRp[KT + k2];
                    acc -= sPow[i + 1] * t1;
                }
                if (MSZ - i < IMGW) {
                    float t2 = 0.0f;
#pragma unroll
                    for (int k2 = MSZ - IMGW + 1; k2 < MSZ; ++k2) t2 += sPow[MSZ - k2] * sRp[KT + k2];
                    acc -= sPow[MSZ - i] * t2;
                }
                sQM[i + 1].y = Cg * acc;
            }
        }
    }
    if (tid == 0) { sQM[0].y = 0.0f; sQM[NP - 1].y = 0.0f; }
    __syncthreads();                                            // B4

    // ---- Phase B: F in registers, spline eval, integrate ----
    float local = 0.0f;
    float term0 = 0.0f, term7 = 0.0f;
    {
        float c1B = half_dt * invSB;
        float Pm = exclB;
#pragma unroll
        for (int e = 0; e < EPT; ++e) {
            int j = base + e;
            float Pj = exclB + prefB[e];
            float Fj = (j == 0) ? 0.0f : (Pm + Pj - sq0B) * c1B;
            float sqe = (e == 0) ? prefB[0] : (prefB[e] - prefB[e - 1]);
            float ft = sqe * invSB;
            int k = (int)(Fj * inv_h);
            if (k < 0) k = 0;
            if (k > NP - 2) k = NP - 2;
            float s = Fj - (float)k * h;
            float2 qm0 = sQM[k];
            float2 qm1 = sQM[k + 1];
            float bco = (qm1.x - qm0.x) * inv_h - h * (2.0f * qm0.y + qm1.y) * (1.0f / 6.0f);
            float cco = 0.5f * qm0.y;
            float dco = (qm1.y - qm0.y) * (inv_h * (1.0f / 6.0f));
            float od  = qm0.x + s * (bco + s * (cco + s * dco));
            float tj  = (float)j * dt;
            float dd  = tj - od;
            float term = dd * dd * ft;
            local += term;
            if (e == 0) term0 = term;
            if (e == EPT - 1) term7 = term;
            Pm = Pj;
        }
    }
    if (tid == 0)       local -= 0.5f * term0;   // trapezoid half-weight at j=0
    if (tid == NTH - 1) local -= 0.5f * term7;   // and at j=NT-1

#pragma unroll
    for (int off = 32; off > 0; off >>= 1) local += __shfl_down(local, off);
    if (lane == 0) sRed[wid] = local;
    __syncthreads();                                            // B5
    if (tid == 0) partial[b] = (sRed[0] + sRed[1] + sRed[2] + sRed[3]) * dt;
}

// fixed-order deterministic reduction of 4096 partials -> scalar
__global__ __launch_bounds__(NTH) void w2loss_reduce(
    const float* __restrict__ partial, float* __restrict__ out)
{
    __shared__ float sRed[4];
    const int tid  = threadIdx.x;
    const int lane = tid & 63;
    const int wid  = tid >> 6;
    float s = 0.0f;
#pragma unroll
    for (int i = 0; i < 16; i += 4) {
        float4 v = *reinterpret_cast<const float4*>(partial + tid * 16 + i);
        s += v.x + v.y + v.z + v.w;
    }
#pragma unroll
    for (int off = 32; off > 0; off >>= 1) s += __shfl_down(s, off);
    if (lane == 0) sRed[wid] = s;
    __syncthreads();
    if (tid == 0) out[0] = sRed[0] + sRed[1] + sRed[2] + sRed[3];
}

extern "C" void kernel_launch(void* const* d_in, const int* in_sizes, int n_in,
                              void* d_out, int out_size, void* d_ws, size_t ws_size,
                              hipStream_t stream) {
    const float* f   = (const float*)d_in[0];
    const float* obs = (const float*)d_in[1];
    float* out     = (float*)d_out;
    float* partial = (float*)d_ws;   // 4096 floats = 16 KB scratch

    w2loss_kernel<<<NBATCH, NTH, 0, stream>>>(f, obs, partial);
    w2loss_reduce<<<1, NTH, 0, stream>>>(partial, out);
}